// Round 1
// baseline (683.489 us; speedup 1.0000x reference)
//
#include <hip/hip_runtime.h>
#include <math.h>

#define N_NODES 50000
#define EDGES   1250000
#define DIM     64
#define NLAYER  3
#define BATCH   4096

// ---------------- CSR build ----------------

__global__ __launch_bounds__(256) void hist_kernel(const int* __restrict__ rows,
                                                   int* __restrict__ cnt) {
    int e = blockIdx.x * 256 + threadIdx.x;
    if (e < EDGES) atomicAdd(&cnt[rows[e]], 1);
}

__global__ __launch_bounds__(1024) void scan_kernel(const int* __restrict__ cnt,
                                                    int* __restrict__ row_ptr,
                                                    int* __restrict__ cursor) {
    __shared__ int buf[1024];
    __shared__ int carry_s;
    int tid = threadIdx.x;
    if (tid == 0) carry_s = 0;
    __syncthreads();
    for (int base = 0; base < N_NODES; base += 1024) {
        int i = base + tid;
        int v = (i < N_NODES) ? cnt[i] : 0;
        buf[tid] = v;
        __syncthreads();
        int sum = v;
        for (int off = 1; off < 1024; off <<= 1) {
            int t = (tid >= off) ? buf[tid - off] : 0;
            __syncthreads();
            sum += t;
            buf[tid] = sum;
            __syncthreads();
        }
        int carry = carry_s;
        int excl = sum - v;
        if (i < N_NODES) {
            int rp = carry + excl;
            row_ptr[i] = rp;
            cursor[i] = rp;
        }
        __syncthreads();
        if (tid == 1023) carry_s = carry + sum;
        __syncthreads();
    }
    if (tid == 0) row_ptr[N_NODES] = carry_s;
}

__global__ __launch_bounds__(256) void scatter_kernel(const int* __restrict__ rows,
                                                      const int* __restrict__ cols,
                                                      const float* __restrict__ vals,
                                                      int* __restrict__ cursor,
                                                      int* __restrict__ csr_col,
                                                      float* __restrict__ csr_val) {
    int e = blockIdx.x * 256 + threadIdx.x;
    if (e < EDGES) {
        int r = rows[e];
        int p = atomicAdd(&cursor[r], 1);
        csr_col[p] = cols[e];
        csr_val[p] = vals[e];
    }
}

// ---------------- SpMM: one wave per row, lane = dim ----------------

__global__ __launch_bounds__(256) void spmm_kernel(const int* __restrict__ row_ptr,
                                                   const int* __restrict__ csr_col,
                                                   const float* __restrict__ csr_val,
                                                   const float* __restrict__ x,
                                                   float* __restrict__ agg) {
    int lane = threadIdx.x & 63;
    int row = blockIdx.x * 4 + (threadIdx.x >> 6);
    if (row >= N_NODES) return;
    int p0 = row_ptr[row], p1 = row_ptr[row + 1];
    float acc = 0.f;
    int p = p0;
    for (; p + 1 < p1; p += 2) {
        int c0 = csr_col[p];
        int c1 = csr_col[p + 1];
        float v0 = csr_val[p];
        float v1 = csr_val[p + 1];
        float x0 = x[(size_t)c0 * DIM + lane];
        float x1 = x[(size_t)c1 * DIM + lane];
        acc += v0 * x0;
        acc += v1 * x1;
    }
    if (p < p1) acc += csr_val[p] * x[(size_t)csr_col[p] * DIM + lane];
    agg[(size_t)row * DIM + lane] = acc;
}

// ---------------- Dense layer ----------------
// y = leaky_relu((agg+x) @ W1^T + b1 + agg * (x @ W2^T + b2), 0.01)

__global__ __launch_bounds__(256) void dense_kernel(const float* __restrict__ x,
                                                    const float* __restrict__ agg,
                                                    const float* __restrict__ w1,
                                                    const float* __restrict__ b1,
                                                    const float* __restrict__ w2,
                                                    const float* __restrict__ b2,
                                                    float* __restrict__ y) {
    __shared__ float w1t[64 * 65];
    __shared__ float w2t[64 * 65];
    __shared__ float b1s[64], b2s[64];
    for (int t = threadIdx.x; t < 4096; t += 256) {
        int i = t >> 6, j = t & 63;
        w1t[j * 65 + i] = w1[t];
        w2t[j * 65 + i] = w2[t];
    }
    if (threadIdx.x < 64) {
        b1s[threadIdx.x] = b1[threadIdx.x];
        b2s[threadIdx.x] = b2[threadIdx.x];
    }
    __syncthreads();

    int lane = threadIdx.x & 63;
    int wid = threadIdx.x >> 6;
    int stride = gridDim.x * 4;
    for (int node = blockIdx.x * 4 + wid; node < N_NODES; node += stride) {
        float xc = x[(size_t)node * DIM + lane];
        float xa = agg[(size_t)node * DIM + lane];
        float xs = xa + xc;
        float s1 = 0.f, s2 = 0.f;
#pragma unroll
        for (int j = 0; j < 64; ++j) {
            float xsj = __shfl(xs, j);
            float xcj = __shfl(xc, j);
            s1 += w1t[j * 65 + lane] * xsj;
            s2 += w2t[j * 65 + lane] * xcj;
        }
        float t = s1 + b1s[lane] + xa * (s2 + b2s[lane]);
        y[(size_t)node * DIM + lane] = (t > 0.f) ? t : 0.01f * t;
    }
}

// ---------------- Per-layer dot contributions ----------------
// dst[i] = dot(x[user[i]], x[pos[i]]) - dot(x[user[i]], x[neg[i]])

__global__ __launch_bounds__(256) void gather_dots_kernel(const float* __restrict__ x,
                                                          const int* __restrict__ user,
                                                          const int* __restrict__ pos,
                                                          const int* __restrict__ neg,
                                                          float* __restrict__ dst) {
    int lane = threadIdx.x & 63;
    int i = blockIdx.x * 4 + (threadIdx.x >> 6);
    if (i >= BATCH) return;
    int ui = user[i], pi = pos[i], ni = neg[i];
    float u = x[(size_t)ui * DIM + lane];
    float p = x[(size_t)pi * DIM + lane];
    float n = x[(size_t)ni * DIM + lane];
    float v = u * (p - n);
#pragma unroll
    for (int off = 32; off; off >>= 1) v += __shfl_xor(v, off);
    if (lane == 0) dst[i] = v;
}

// ---------------- Final loss ----------------

__global__ __launch_bounds__(1024) void loss_kernel(const float* __restrict__ dots,
                                                    float* __restrict__ out) {
    __shared__ float red[16];
    int tid = threadIdx.x;
    float acc = 0.f;
    for (int i = tid; i < BATCH; i += 1024) {
        float d = dots[i] + dots[BATCH + i] + dots[2 * BATCH + i] + dots[3 * BATCH + i];
        // -log_sigmoid(d) = max(-d, 0) + log1p(exp(-|d|))
        acc += fmaxf(-d, 0.f) + log1pf(expf(-fabsf(d)));
    }
#pragma unroll
    for (int off = 32; off; off >>= 1) acc += __shfl_xor(acc, off);
    if ((tid & 63) == 0) red[tid >> 6] = acc;
    __syncthreads();
    if (tid < 16) {
        float v = red[tid];
#pragma unroll
        for (int off = 8; off; off >>= 1) v += __shfl_xor(v, off);
        if (tid == 0) out[0] = v;
    }
}

// ---------------- Launch ----------------

extern "C" void kernel_launch(void* const* d_in, const int* in_sizes, int n_in,
                              void* d_out, int out_size, void* d_ws, size_t ws_size,
                              hipStream_t stream) {
    const float* emb  = (const float*)d_in[0];
    const float* w1_w = (const float*)d_in[1];
    const float* w1_b = (const float*)d_in[2];
    const float* w2_w = (const float*)d_in[3];
    const float* w2_b = (const float*)d_in[4];
    const float* vals = (const float*)d_in[5];
    const int* rows = (const int*)d_in[6];
    const int* cols = (const int*)d_in[7];
    const int* user = (const int*)d_in[8];
    const int* pos  = (const int*)d_in[9];
    const int* neg  = (const int*)d_in[10];
    float* out = (float*)d_out;

    char* w = (char*)d_ws;
    float* bufA = (float*)w;  w += (size_t)N_NODES * DIM * 4;
    float* bufB = (float*)w;  w += (size_t)N_NODES * DIM * 4;
    float* agg  = (float*)w;  w += (size_t)N_NODES * DIM * 4;
    int* row_ptr = (int*)w;   w += (((size_t)(N_NODES + 1) * 4) + 255) / 256 * 256;
    int* row_cnt = (int*)w;   w += (size_t)N_NODES * 4;
    int* cursor  = (int*)w;   w += (size_t)N_NODES * 4;
    int* csr_col = (int*)w;   w += (size_t)EDGES * 4;
    float* csr_val = (float*)w; w += (size_t)EDGES * 4;
    float* dots = (float*)w;  w += (size_t)4 * BATCH * 4;

    // CSR build (per call; inputs never mutated)
    hipMemsetAsync(row_cnt, 0, (size_t)N_NODES * 4, stream);
    hist_kernel<<<(EDGES + 255) / 256, 256, 0, stream>>>(rows, row_cnt);
    scan_kernel<<<1, 1024, 0, stream>>>(row_cnt, row_ptr, cursor);
    scatter_kernel<<<(EDGES + 255) / 256, 256, 0, stream>>>(rows, cols, vals, cursor,
                                                            csr_col, csr_val);

    // layer 0 contributions read emb directly
    gather_dots_kernel<<<BATCH / 4, 256, 0, stream>>>(emb, user, pos, neg, dots);

    const float* x = emb;
    float* bufs[2] = {bufA, bufB};
    for (int l = 0; l < NLAYER; ++l) {
        float* y = bufs[l & 1];
        spmm_kernel<<<(N_NODES + 3) / 4, 256, 0, stream>>>(row_ptr, csr_col, csr_val, x, agg);
        dense_kernel<<<1024, 256, 0, stream>>>(x, agg,
                                               w1_w + (size_t)l * DIM * DIM, w1_b + (size_t)l * DIM,
                                               w2_w + (size_t)l * DIM * DIM, w2_b + (size_t)l * DIM,
                                               y);
        gather_dots_kernel<<<BATCH / 4, 256, 0, stream>>>(y, user, pos, neg,
                                                          dots + (size_t)(l + 1) * BATCH);
        x = y;
    }

    loss_kernel<<<1, 1024, 0, stream>>>(dots, out);
}

// Round 2
// 482.148 us; speedup vs baseline: 1.4176x; 1.4176x over previous
//
#include <hip/hip_runtime.h>
#include <math.h>

#define N_NODES 50000
#define EDGES   1250000
#define DIM     64
#define NLAYER  3
#define BATCH   4096

// ---------------- CSR build ----------------

__global__ __launch_bounds__(256) void hist_kernel(const int* __restrict__ rows,
                                                   int* __restrict__ cnt) {
    int e = blockIdx.x * 256 + threadIdx.x;
    if (e < EDGES) atomicAdd(&cnt[rows[e]], 1);
}

__global__ __launch_bounds__(1024) void scan_kernel(const int* __restrict__ cnt,
                                                    int* __restrict__ row_ptr,
                                                    int* __restrict__ cursor) {
    __shared__ int wsum[16];
    __shared__ int carry_s;
    int tid = threadIdx.x;
    int lane = tid & 63, wid = tid >> 6;
    if (tid == 0) carry_s = 0;
    __syncthreads();
    for (int base = 0; base < N_NODES; base += 1024) {
        int i = base + tid;
        int v = (i < N_NODES) ? cnt[i] : 0;
        int s = v;
#pragma unroll
        for (int off = 1; off < 64; off <<= 1) {
            int t = __shfl_up(s, off);
            if (lane >= off) s += t;
        }
        if (lane == 63) wsum[wid] = s;
        __syncthreads();
        if (wid == 0) {
            int xv = (lane < 16) ? wsum[lane] : 0;
#pragma unroll
            for (int off = 1; off < 16; off <<= 1) {
                int t = __shfl_up(xv, off);
                if (lane >= off) xv += t;
            }
            if (lane < 16) wsum[lane] = xv;
        }
        __syncthreads();
        int woff = wid ? wsum[wid - 1] : 0;
        int carry = carry_s;
        int incl = carry + woff + s;
        if (i < N_NODES) {
            row_ptr[i] = incl - v;
            cursor[i] = incl - v;
        }
        __syncthreads();
        if (tid == 1023) carry_s = incl;
        __syncthreads();
    }
    if (tid == 0) row_ptr[N_NODES] = carry_s;
}

__global__ __launch_bounds__(256) void scatter_kernel(const int* __restrict__ rows,
                                                      const int* __restrict__ cols,
                                                      const float* __restrict__ vals,
                                                      int* __restrict__ cursor,
                                                      int2* __restrict__ csr) {
    int e = blockIdx.x * 256 + threadIdx.x;
    if (e < EDGES) {
        int r = rows[e];
        int p = atomicAdd(&cursor[r], 1);
        csr[p] = make_int2(cols[e], __float_as_int(vals[e]));
    }
}

// ---------------- SpMM: one wave per row, 4 edge-groups x 16 lanes x float4 ----

__global__ __launch_bounds__(256) void spmm_kernel(const int* __restrict__ row_ptr,
                                                   const int2* __restrict__ csr,
                                                   const float* __restrict__ x,
                                                   float* __restrict__ agg) {
    int lane = threadIdx.x & 63;
    int g = lane >> 4;     // edge group 0..3
    int sl = lane & 15;    // dim quarter
    int row = blockIdx.x * 4 + (threadIdx.x >> 6);
    if (row >= N_NODES) return;
    int p0 = row_ptr[row], p1 = row_ptr[row + 1];
    float4 acc = make_float4(0.f, 0.f, 0.f, 0.f);
    int p = p0;
    for (; p + 8 <= p1; p += 8) {
        int2 a = csr[p + g];
        int2 b = csr[p + 4 + g];
        float4 xa = *(const float4*)(x + (size_t)a.x * DIM + sl * 4);
        float4 xb = *(const float4*)(x + (size_t)b.x * DIM + sl * 4);
        float va = __int_as_float(a.y);
        float vb = __int_as_float(b.y);
        acc.x += va * xa.x; acc.y += va * xa.y; acc.z += va * xa.z; acc.w += va * xa.w;
        acc.x += vb * xb.x; acc.y += vb * xb.y; acc.z += vb * xb.z; acc.w += vb * xb.w;
    }
    for (; p < p1; p += 4) {
        int pe = p + g;
        if (pe < p1) {
            int2 a = csr[pe];
            float4 xa = *(const float4*)(x + (size_t)a.x * DIM + sl * 4);
            float va = __int_as_float(a.y);
            acc.x += va * xa.x; acc.y += va * xa.y; acc.z += va * xa.z; acc.w += va * xa.w;
        }
    }
#pragma unroll
    for (int m = 16; m <= 32; m <<= 1) {
        acc.x += __shfl_xor(acc.x, m);
        acc.y += __shfl_xor(acc.y, m);
        acc.z += __shfl_xor(acc.z, m);
        acc.w += __shfl_xor(acc.w, m);
    }
    if (lane < 16) *(float4*)(agg + (size_t)row * DIM + lane * 4) = acc;
}

// ---------------- Dense layer (LDS-tiled) ----------------
// y = leaky_relu((agg+x) @ W1^T + b1 + agg * (x @ W2^T + b2), 0.01)
// Tile = 32 nodes. xsT/xcT stored [j][n] (pad 36). W stored [j][d] (no pad).

#define TNODES 32
#define XPAD   36

__global__ __launch_bounds__(256) void dense_kernel(const float* __restrict__ x,
                                                    const float* __restrict__ agg,
                                                    const float* __restrict__ w1,
                                                    const float* __restrict__ b1,
                                                    const float* __restrict__ w2,
                                                    const float* __restrict__ b2,
                                                    float* __restrict__ y) {
    __shared__ float xsT[64 * XPAD];
    __shared__ float xcT[64 * XPAD];
    __shared__ float w1T[64 * 64];
    __shared__ float w2T[64 * 64];

    int tid = threadIdx.x;
    // stage W transposed: w?T[j*64 + d] = w?[d*64 + j]
    for (int f = tid; f < 4096; f += 256) {
        int dout = f >> 6, j = f & 63;
        w1T[j * 64 + dout] = w1[f];
        w2T[j * 64 + dout] = w2[f];
    }

    int n0 = blockIdx.x * TNODES;
    // stage x tiles: xsT[j][n] = x+agg, xcT[j][n] = x
    for (int f = tid; f < TNODES * 64; f += 256) {
        int n = f >> 6, j = f & 63;
        int node = n0 + n;
        int nc = (node < N_NODES) ? node : (N_NODES - 1);
        float xv = x[(size_t)nc * DIM + j];
        float av = agg[(size_t)nc * DIM + j];
        xsT[j * XPAD + n] = xv + av;
        xcT[j * XPAD + n] = xv;
    }
    __syncthreads();

    int d = tid & 63;
    int w = tid >> 6;           // wave id: nodes [w*8, w*8+8)
    float s1[8] = {0, 0, 0, 0, 0, 0, 0, 0};
    float s2[8] = {0, 0, 0, 0, 0, 0, 0, 0};
#pragma unroll 4
    for (int j = 0; j < 64; ++j) {
        float w1v = w1T[j * 64 + d];
        float w2v = w2T[j * 64 + d];
        const float* xsp = &xsT[j * XPAD + w * 8];
        const float* xcp = &xcT[j * XPAD + w * 8];
        float4 xs0 = *(const float4*)(xsp);
        float4 xs1 = *(const float4*)(xsp + 4);
        float4 xc0 = *(const float4*)(xcp);
        float4 xc1 = *(const float4*)(xcp + 4);
        s1[0] += w1v * xs0.x; s1[1] += w1v * xs0.y; s1[2] += w1v * xs0.z; s1[3] += w1v * xs0.w;
        s1[4] += w1v * xs1.x; s1[5] += w1v * xs1.y; s1[6] += w1v * xs1.z; s1[7] += w1v * xs1.w;
        s2[0] += w2v * xc0.x; s2[1] += w2v * xc0.y; s2[2] += w2v * xc0.z; s2[3] += w2v * xc0.w;
        s2[4] += w2v * xc1.x; s2[5] += w2v * xc1.y; s2[6] += w2v * xc1.z; s2[7] += w2v * xc1.w;
    }
    float b1v = b1[d], b2v = b2[d];
#pragma unroll
    for (int k = 0; k < 8; ++k) {
        int node = n0 + w * 8 + k;
        if (node < N_NODES) {
            float xa = agg[(size_t)node * DIM + d];
            float t = s1[k] + b1v + xa * (s2[k] + b2v);
            y[(size_t)node * DIM + d] = (t > 0.f) ? t : 0.01f * t;
        }
    }
}

// ---------------- Per-layer dot contributions ----------------

__global__ __launch_bounds__(256) void gather_dots_kernel(const float* __restrict__ x,
                                                          const int* __restrict__ user,
                                                          const int* __restrict__ pos,
                                                          const int* __restrict__ neg,
                                                          float* __restrict__ dst) {
    int lane = threadIdx.x & 63;
    int i = blockIdx.x * 4 + (threadIdx.x >> 6);
    if (i >= BATCH) return;
    int ui = user[i], pi = pos[i], ni = neg[i];
    float u = x[(size_t)ui * DIM + lane];
    float p = x[(size_t)pi * DIM + lane];
    float n = x[(size_t)ni * DIM + lane];
    float v = u * (p - n);
#pragma unroll
    for (int off = 32; off; off >>= 1) v += __shfl_xor(v, off);
    if (lane == 0) dst[i] = v;
}

// ---------------- Final loss ----------------

__global__ __launch_bounds__(1024) void loss_kernel(const float* __restrict__ dots,
                                                    float* __restrict__ out) {
    __shared__ float red[16];
    int tid = threadIdx.x;
    float acc = 0.f;
    for (int i = tid; i < BATCH; i += 1024) {
        float d = dots[i] + dots[BATCH + i] + dots[2 * BATCH + i] + dots[3 * BATCH + i];
        acc += fmaxf(-d, 0.f) + log1pf(expf(-fabsf(d)));
    }
#pragma unroll
    for (int off = 32; off; off >>= 1) acc += __shfl_xor(acc, off);
    if ((tid & 63) == 0) red[tid >> 6] = acc;
    __syncthreads();
    if (tid < 16) {
        float v = red[tid];
#pragma unroll
        for (int off = 8; off; off >>= 1) v += __shfl_xor(v, off);
        if (tid == 0) out[0] = v;
    }
}

// ---------------- Launch ----------------

extern "C" void kernel_launch(void* const* d_in, const int* in_sizes, int n_in,
                              void* d_out, int out_size, void* d_ws, size_t ws_size,
                              hipStream_t stream) {
    const float* emb  = (const float*)d_in[0];
    const float* w1_w = (const float*)d_in[1];
    const float* w1_b = (const float*)d_in[2];
    const float* w2_w = (const float*)d_in[3];
    const float* w2_b = (const float*)d_in[4];
    const float* vals = (const float*)d_in[5];
    const int* rows = (const int*)d_in[6];
    const int* cols = (const int*)d_in[7];
    const int* user = (const int*)d_in[8];
    const int* pos  = (const int*)d_in[9];
    const int* neg  = (const int*)d_in[10];
    float* out = (float*)d_out;

    char* w = (char*)d_ws;
    float* bufA = (float*)w;  w += (size_t)N_NODES * DIM * 4;
    float* bufB = (float*)w;  w += (size_t)N_NODES * DIM * 4;
    float* agg  = (float*)w;  w += (size_t)N_NODES * DIM * 4;
    int* row_ptr = (int*)w;   w += (((size_t)(N_NODES + 1) * 4) + 255) / 256 * 256;
    int* row_cnt = (int*)w;   w += (size_t)N_NODES * 4;
    int* cursor  = (int*)w;   w += (size_t)N_NODES * 4;
    int2* csr    = (int2*)w;  w += (size_t)EDGES * 8;
    float* dots = (float*)w;  w += (size_t)4 * BATCH * 4;

    hipMemsetAsync(row_cnt, 0, (size_t)N_NODES * 4, stream);
    hist_kernel<<<(EDGES + 255) / 256, 256, 0, stream>>>(rows, row_cnt);
    scan_kernel<<<1, 1024, 0, stream>>>(row_cnt, row_ptr, cursor);
    scatter_kernel<<<(EDGES + 255) / 256, 256, 0, stream>>>(rows, cols, vals, cursor, csr);

    gather_dots_kernel<<<BATCH / 4, 256, 0, stream>>>(emb, user, pos, neg, dots);

    const float* x = emb;
    float* bufs[2] = {bufA, bufB};
    for (int l = 0; l < NLAYER; ++l) {
        float* y = bufs[l & 1];
        spmm_kernel<<<(N_NODES + 3) / 4, 256, 0, stream>>>(row_ptr, csr, x, agg);
        dense_kernel<<<(N_NODES + TNODES - 1) / TNODES, 256, 0, stream>>>(
            x, agg,
            w1_w + (size_t)l * DIM * DIM, w1_b + (size_t)l * DIM,
            w2_w + (size_t)l * DIM * DIM, w2_b + (size_t)l * DIM,
            y);
        gather_dots_kernel<<<BATCH / 4, 256, 0, stream>>>(y, user, pos, neg,
                                                          dots + (size_t)(l + 1) * BATCH);
        x = y;
    }

    loss_kernel<<<1, 1024, 0, stream>>>(dots, out);
}

// Round 3
// 361.348 us; speedup vs baseline: 1.8915x; 1.3343x over previous
//
#include <hip/hip_runtime.h>
#include <math.h>

#define N_NODES 50000
#define EDGES   1250000
#define DIM     64
#define NLAYER  3
#define BATCH   4096

#define NBUCK 196   // coarse buckets: bucket = row >> 8 (256 rows each)
#define RPB   256   // rows per bucket
#define NABLK 128   // phase-A blocks

// ---------------- Phase A1: per-block bucket histogram ----------------

__global__ __launch_bounds__(256) void bucket_hist_kernel(const int* __restrict__ rows,
                                                          int* __restrict__ bhist) {
    __shared__ int h[NBUCK];
    for (int i = threadIdx.x; i < NBUCK; i += 256) h[i] = 0;
    __syncthreads();
    int per = (EDGES + NABLK - 1) / NABLK;
    int e0 = blockIdx.x * per;
    int e1 = min(e0 + per, EDGES);
    for (int e = e0 + threadIdx.x; e < e1; e += 256)
        atomicAdd(&h[rows[e] >> 8], 1);
    __syncthreads();
    for (int i = threadIdx.x; i < NBUCK; i += 256)
        bhist[i * NABLK + blockIdx.x] = h[i];
}

// ---------------- Phase A2: exclusive scan of bhist (bucket-major) ----------------

__global__ __launch_bounds__(1024) void bucket_scan_kernel(const int* __restrict__ bhist,
                                                           int* __restrict__ boffs) {
    __shared__ int wsum[16];
    __shared__ int carry_s;
    int tid = threadIdx.x, lane = tid & 63, wid = tid >> 6;
    if (tid == 0) carry_s = 0;
    __syncthreads();
    const int TOTAL = NBUCK * NABLK;
    for (int basei = 0; basei < TOTAL; basei += 1024) {
        int i = basei + tid;
        int v = (i < TOTAL) ? bhist[i] : 0;
        int s = v;
#pragma unroll
        for (int off = 1; off < 64; off <<= 1) {
            int t = __shfl_up(s, off);
            if (lane >= off) s += t;
        }
        if (lane == 63) wsum[wid] = s;
        __syncthreads();
        if (wid == 0) {
            int xv = (lane < 16) ? wsum[lane] : 0;
#pragma unroll
            for (int off = 1; off < 16; off <<= 1) {
                int t = __shfl_up(xv, off);
                if (lane >= off) xv += t;
            }
            if (lane < 16) wsum[lane] = xv;
        }
        __syncthreads();
        int woff = wid ? wsum[wid - 1] : 0;
        int carry = carry_s;
        if (i < TOTAL) boffs[i] = carry + woff + s - v;
        __syncthreads();
        if (tid == 1023) carry_s = carry + woff + s;
        __syncthreads();
    }
}

// ---------------- Phase A3: scatter edges into bucket staging ----------------
// staging[p] = ((row&255)<<16 | col, val_bits); block-private contiguous runs.

__global__ __launch_bounds__(256) void bucket_scatter_kernel(const int* __restrict__ rows,
                                                             const int* __restrict__ cols,
                                                             const float* __restrict__ vals,
                                                             const int* __restrict__ boffs,
                                                             int2* __restrict__ staging) {
    __shared__ int cur[NBUCK];
    for (int i = threadIdx.x; i < NBUCK; i += 256)
        cur[i] = boffs[i * NABLK + blockIdx.x];
    __syncthreads();
    int per = (EDGES + NABLK - 1) / NABLK;
    int e0 = blockIdx.x * per;
    int e1 = min(e0 + per, EDGES);
    for (int e = e0 + threadIdx.x; e < e1; e += 256) {
        int r = rows[e];
        int p = atomicAdd(&cur[r >> 8], 1);
        staging[p] = make_int2(((r & 255) << 16) | cols[e], __float_as_int(vals[e]));
    }
}

// ---------------- Phase B: per-bucket row_ptr + final CSR ----------------

__global__ __launch_bounds__(256) void csr_build_kernel(const int* __restrict__ boffs,
                                                        const int2* __restrict__ staging,
                                                        int* __restrict__ row_ptr,
                                                        int2* __restrict__ csr) {
    __shared__ int rcur[RPB];
    __shared__ int wred[4];
    int b = blockIdx.x;
    int base = boffs[b * NABLK];
    int end = (b == NBUCK - 1) ? EDGES : boffs[(b + 1) * NABLK];
    int tid = threadIdx.x;
    rcur[tid] = 0;
    __syncthreads();
    for (int p = base + tid; p < end; p += 256)
        atomicAdd(&rcur[staging[p].x >> 16], 1);
    __syncthreads();
    // exclusive scan of rcur[256] (4 waves)
    int lane = tid & 63, wid = tid >> 6;
    int v = rcur[tid];
    int s = v;
#pragma unroll
    for (int off = 1; off < 64; off <<= 1) {
        int t = __shfl_up(s, off);
        if (lane >= off) s += t;
    }
    if (lane == 63) wred[wid] = s;
    __syncthreads();
    if (tid == 0) {
        int a = 0;
#pragma unroll
        for (int i = 0; i < 4; ++i) { int t = wred[i]; wred[i] = a; a += t; }
    }
    __syncthreads();
    int excl = wred[wid] + s - v;
    __syncthreads();
    rcur[tid] = base + excl;
    int row = b * RPB + tid;
    if (row < N_NODES) row_ptr[row] = base + excl;
    if (b == NBUCK - 1 && tid == 0) row_ptr[N_NODES] = EDGES;
    __syncthreads();
    for (int p = base + tid; p < end; p += 256) {
        int2 e = staging[p];
        int pos = atomicAdd(&rcur[e.x >> 16], 1);
        csr[pos] = make_int2(e.x & 0xFFFF, e.y);
    }
}

// ---------------- SpMM: one wave per row, 4 edge-groups x 16 lanes x float4 ----

__global__ __launch_bounds__(256) void spmm_kernel(const int* __restrict__ row_ptr,
                                                   const int2* __restrict__ csr,
                                                   const float* __restrict__ x,
                                                   float* __restrict__ agg) {
    int lane = threadIdx.x & 63;
    int g = lane >> 4;     // edge group 0..3
    int sl = lane & 15;    // dim quarter
    int row = blockIdx.x * 4 + (threadIdx.x >> 6);
    if (row >= N_NODES) return;
    int p0 = row_ptr[row], p1 = row_ptr[row + 1];
    float4 acc = make_float4(0.f, 0.f, 0.f, 0.f);
    int p = p0;
    for (; p + 16 <= p1; p += 16) {
        int2 a = csr[p + g];
        int2 b = csr[p + 4 + g];
        int2 c = csr[p + 8 + g];
        int2 d = csr[p + 12 + g];
        float4 xa = *(const float4*)(x + (size_t)a.x * DIM + sl * 4);
        float4 xb = *(const float4*)(x + (size_t)b.x * DIM + sl * 4);
        float4 xc = *(const float4*)(x + (size_t)c.x * DIM + sl * 4);
        float4 xd = *(const float4*)(x + (size_t)d.x * DIM + sl * 4);
        float va = __int_as_float(a.y), vb = __int_as_float(b.y);
        float vc = __int_as_float(c.y), vd = __int_as_float(d.y);
        acc.x += va * xa.x; acc.y += va * xa.y; acc.z += va * xa.z; acc.w += va * xa.w;
        acc.x += vb * xb.x; acc.y += vb * xb.y; acc.z += vb * xb.z; acc.w += vb * xb.w;
        acc.x += vc * xc.x; acc.y += vc * xc.y; acc.z += vc * xc.z; acc.w += vc * xc.w;
        acc.x += vd * xd.x; acc.y += vd * xd.y; acc.z += vd * xd.z; acc.w += vd * xd.w;
    }
    for (; p + 8 <= p1; p += 8) {
        int2 a = csr[p + g];
        int2 b = csr[p + 4 + g];
        float4 xa = *(const float4*)(x + (size_t)a.x * DIM + sl * 4);
        float4 xb = *(const float4*)(x + (size_t)b.x * DIM + sl * 4);
        float va = __int_as_float(a.y), vb = __int_as_float(b.y);
        acc.x += va * xa.x; acc.y += va * xa.y; acc.z += va * xa.z; acc.w += va * xa.w;
        acc.x += vb * xb.x; acc.y += vb * xb.y; acc.z += vb * xb.z; acc.w += vb * xb.w;
    }
    for (; p < p1; p += 4) {
        int pe = p + g;
        if (pe < p1) {
            int2 a = csr[pe];
            float4 xa = *(const float4*)(x + (size_t)a.x * DIM + sl * 4);
            float va = __int_as_float(a.y);
            acc.x += va * xa.x; acc.y += va * xa.y; acc.z += va * xa.z; acc.w += va * xa.w;
        }
    }
#pragma unroll
    for (int m = 16; m <= 32; m <<= 1) {
        acc.x += __shfl_xor(acc.x, m);
        acc.y += __shfl_xor(acc.y, m);
        acc.z += __shfl_xor(acc.z, m);
        acc.w += __shfl_xor(acc.w, m);
    }
    if (lane < 16) *(float4*)(agg + (size_t)row * DIM + lane * 4) = acc;
}

// ---------------- Dense layer (LDS-tiled) ----------------

#define TNODES 32
#define XPAD   36

__global__ __launch_bounds__(256) void dense_kernel(const float* __restrict__ x,
                                                    const float* __restrict__ agg,
                                                    const float* __restrict__ w1,
                                                    const float* __restrict__ b1,
                                                    const float* __restrict__ w2,
                                                    const float* __restrict__ b2,
                                                    float* __restrict__ y) {
    __shared__ float xsT[64 * XPAD];
    __shared__ float xcT[64 * XPAD];
    __shared__ float w1T[64 * 64];
    __shared__ float w2T[64 * 64];

    int tid = threadIdx.x;
    for (int f = tid; f < 4096; f += 256) {
        int dout = f >> 6, j = f & 63;
        w1T[j * 64 + dout] = w1[f];
        w2T[j * 64 + dout] = w2[f];
    }

    int n0 = blockIdx.x * TNODES;
    for (int f = tid; f < TNODES * 64; f += 256) {
        int n = f >> 6, j = f & 63;
        int node = n0 + n;
        int nc = (node < N_NODES) ? node : (N_NODES - 1);
        float xv = x[(size_t)nc * DIM + j];
        float av = agg[(size_t)nc * DIM + j];
        xsT[j * XPAD + n] = xv + av;
        xcT[j * XPAD + n] = xv;
    }
    __syncthreads();

    int d = tid & 63;
    int w = tid >> 6;
    float s1[8] = {0, 0, 0, 0, 0, 0, 0, 0};
    float s2[8] = {0, 0, 0, 0, 0, 0, 0, 0};
#pragma unroll 4
    for (int j = 0; j < 64; ++j) {
        float w1v = w1T[j * 64 + d];
        float w2v = w2T[j * 64 + d];
        const float* xsp = &xsT[j * XPAD + w * 8];
        const float* xcp = &xcT[j * XPAD + w * 8];
        float4 xs0 = *(const float4*)(xsp);
        float4 xs1 = *(const float4*)(xsp + 4);
        float4 xc0 = *(const float4*)(xcp);
        float4 xc1 = *(const float4*)(xcp + 4);
        s1[0] += w1v * xs0.x; s1[1] += w1v * xs0.y; s1[2] += w1v * xs0.z; s1[3] += w1v * xs0.w;
        s1[4] += w1v * xs1.x; s1[5] += w1v * xs1.y; s1[6] += w1v * xs1.z; s1[7] += w1v * xs1.w;
        s2[0] += w2v * xc0.x; s2[1] += w2v * xc0.y; s2[2] += w2v * xc0.z; s2[3] += w2v * xc0.w;
        s2[4] += w2v * xc1.x; s2[5] += w2v * xc1.y; s2[6] += w2v * xc1.z; s2[7] += w2v * xc1.w;
    }
    float b1v = b1[d], b2v = b2[d];
#pragma unroll
    for (int k = 0; k < 8; ++k) {
        int node = n0 + w * 8 + k;
        if (node < N_NODES) {
            float xa = agg[(size_t)node * DIM + d];
            float t = s1[k] + b1v + xa * (s2[k] + b2v);
            y[(size_t)node * DIM + d] = (t > 0.f) ? t : 0.01f * t;
        }
    }
}

// ---------------- Per-layer dot contributions ----------------

__global__ __launch_bounds__(256) void gather_dots_kernel(const float* __restrict__ x,
                                                          const int* __restrict__ user,
                                                          const int* __restrict__ pos,
                                                          const int* __restrict__ neg,
                                                          float* __restrict__ dst) {
    int lane = threadIdx.x & 63;
    int i = blockIdx.x * 4 + (threadIdx.x >> 6);
    if (i >= BATCH) return;
    int ui = user[i], pi = pos[i], ni = neg[i];
    float u = x[(size_t)ui * DIM + lane];
    float p = x[(size_t)pi * DIM + lane];
    float n = x[(size_t)ni * DIM + lane];
    float v = u * (p - n);
#pragma unroll
    for (int off = 32; off; off >>= 1) v += __shfl_xor(v, off);
    if (lane == 0) dst[i] = v;
}

// ---------------- Final loss ----------------

__global__ __launch_bounds__(1024) void loss_kernel(const float* __restrict__ dots,
                                                    float* __restrict__ out) {
    __shared__ float red[16];
    int tid = threadIdx.x;
    float acc = 0.f;
    for (int i = tid; i < BATCH; i += 1024) {
        float d = dots[i] + dots[BATCH + i] + dots[2 * BATCH + i] + dots[3 * BATCH + i];
        acc += fmaxf(-d, 0.f) + log1pf(expf(-fabsf(d)));
    }
#pragma unroll
    for (int off = 32; off; off >>= 1) acc += __shfl_xor(acc, off);
    if ((tid & 63) == 0) red[tid >> 6] = acc;
    __syncthreads();
    if (tid < 16) {
        float v = red[tid];
#pragma unroll
        for (int off = 8; off; off >>= 1) v += __shfl_xor(v, off);
        if (tid == 0) out[0] = v;
    }
}

// ---------------- Launch ----------------

extern "C" void kernel_launch(void* const* d_in, const int* in_sizes, int n_in,
                              void* d_out, int out_size, void* d_ws, size_t ws_size,
                              hipStream_t stream) {
    const float* emb  = (const float*)d_in[0];
    const float* w1_w = (const float*)d_in[1];
    const float* w1_b = (const float*)d_in[2];
    const float* w2_w = (const float*)d_in[3];
    const float* w2_b = (const float*)d_in[4];
    const float* vals = (const float*)d_in[5];
    const int* rows = (const int*)d_in[6];
    const int* cols = (const int*)d_in[7];
    const int* user = (const int*)d_in[8];
    const int* pos  = (const int*)d_in[9];
    const int* neg  = (const int*)d_in[10];
    float* out = (float*)d_out;

    char* w = (char*)d_ws;
    float* bufA = (float*)w;  w += (size_t)N_NODES * DIM * 4;   // also CSR staging (10MB < 12.8MB)
    float* bufB = (float*)w;  w += (size_t)N_NODES * DIM * 4;
    float* agg  = (float*)w;  w += (size_t)N_NODES * DIM * 4;
    int* row_ptr = (int*)w;   w += (((size_t)(N_NODES + 1) * 4) + 255) / 256 * 256;
    int2* csr    = (int2*)w;  w += (size_t)EDGES * 8;
    int* bhist   = (int*)w;   w += (size_t)NBUCK * NABLK * 4;
    int* boffs   = (int*)w;   w += (size_t)NBUCK * NABLK * 4;
    float* dots = (float*)w;  w += (size_t)4 * BATCH * 4;

    int2* staging = (int2*)bufA;  // dense layer 0 writes bufA only after B consumed staging

    bucket_hist_kernel<<<NABLK, 256, 0, stream>>>(rows, bhist);
    bucket_scan_kernel<<<1, 1024, 0, stream>>>(bhist, boffs);
    bucket_scatter_kernel<<<NABLK, 256, 0, stream>>>(rows, cols, vals, boffs, staging);
    csr_build_kernel<<<NBUCK, 256, 0, stream>>>(boffs, staging, row_ptr, csr);

    gather_dots_kernel<<<BATCH / 4, 256, 0, stream>>>(emb, user, pos, neg, dots);

    const float* x = emb;
    float* bufs[2] = {bufA, bufB};
    for (int l = 0; l < NLAYER; ++l) {
        float* y = bufs[l & 1];
        spmm_kernel<<<(N_NODES + 3) / 4, 256, 0, stream>>>(row_ptr, csr, x, agg);
        dense_kernel<<<(N_NODES + TNODES - 1) / TNODES, 256, 0, stream>>>(
            x, agg,
            w1_w + (size_t)l * DIM * DIM, w1_b + (size_t)l * DIM,
            w2_w + (size_t)l * DIM * DIM, w2_b + (size_t)l * DIM,
            y);
        gather_dots_kernel<<<BATCH / 4, 256, 0, stream>>>(y, user, pos, neg,
                                                          dots + (size_t)(l + 1) * BATCH);
        x = y;
    }

    loss_kernel<<<1, 1024, 0, stream>>>(dots, out);
}